// Round 1
// baseline (1012.856 us; speedup 1.0000x reference)
//
#include <hip/hip_runtime.h>
#include <hip/hip_bf16.h>
#include <stdint.h>

typedef float  f32x4 __attribute__((ext_vector_type(4)));
typedef short  s16x8 __attribute__((ext_vector_type(8)));

__device__ __forceinline__ short f2bf(float f) {
  union { float f; unsigned u; } x; x.f = f;
  unsigned r = x.u + 0x7fffu + ((x.u >> 16) & 1u);
  return (short)(r >> 16);
}

// ---------------- time embedding: t/1000 -> Linear(1,32) -> ReLU -> Linear(32,32)
__global__ void k_time_embed(const int* __restrict__ t, const float* __restrict__ w1,
                             const float* __restrict__ b1, const float* __restrict__ w2,
                             const float* __restrict__ b2, float* __restrict__ out) {
  __shared__ float h[32];
  int j = threadIdx.x;
  float tin = (float)t[0] / 1000.0f;
  if (j < 32) h[j] = fmaxf(tin * w1[j] + b1[j], 0.f);
  __syncthreads();
  if (j < 32) {
    float acc = b2[j];
    for (int k = 0; k < 32; ++k) acc += h[k] * w2[k * 32 + j];
    out[j] = acc;
  }
}

// ---------------- x_input = [x_t | cond | t_embed], float4 per thread
__global__ void k_build_xin(const float* __restrict__ xt, const float* __restrict__ cond,
                            const float* __restrict__ temb, float* __restrict__ X, int n) {
  int i = blockIdx.x * 256 + threadIdx.x;   // over n*32 float4
  if (i >= n * 32) return;
  int node = i >> 5, c4 = i & 31;
  float4 v;
  if (c4 < 16)      v = *(const float4*)&xt[(size_t)node * 64 + c4 * 4];
  else if (c4 < 24) v = *(const float4*)&cond[(c4 - 16) * 4];
  else              v = *(const float4*)&temb[(c4 - 24) * 4];
  *(float4*)&X[(size_t)node * 128 + c4 * 4] = v;
}

__global__ void k_copy4(const float4* __restrict__ in, float4* __restrict__ out, size_t n4) {
  size_t i = blockIdx.x * (size_t)256 + threadIdx.x;
  size_t stride = (size_t)gridDim.x * 256;
  for (; i < n4; i += stride) out[i] = in[i];
}

__global__ void k_copyf(const float* __restrict__ in, float* __restrict__ out, int n) {
  int i = blockIdx.x * 256 + threadIdx.x;
  if (i < n) out[i] = in[i];
}

// ---------------- pack a [128][COLS] f32 weight into bf16 MFMA B-fragment layout
// out[((kt*NT+nt)*64 + lane)*8 + j] = bf16(W[(kt*32 + (lane>>4)*8 + j)][nt*16 + (lane&15)])
template<int COLS>
__global__ void k_pack_w(const float* __restrict__ W, short* __restrict__ out) {
  const int NT = COLS / 16;
  int i = blockIdx.x * 256 + threadIdx.x;
  if (i >= 128 * COLS) return;
  int j = i & 7, l = (i >> 3) & 63;
  int nt = (i >> 9) % NT;
  int kt = (i >> 9) / NT;
  int k = kt * 32 + ((l >> 4) * 8) + j;
  int ncol = nt * 16 + (l & 15);
  out[i] = f2bf(W[(size_t)k * COLS + ncol]);
}

// ---------------- node GEMM via MFMA: C[n][COLS] = bf16(X[n][128]) @ Wpacked (+bias)
template<int COLS>
__global__ __launch_bounds__(256)
void k_mgemm(const float* __restrict__ X, const short* __restrict__ Wp,
             const float* __restrict__ bias, float* __restrict__ C, int n) {
  const int NT = COLS / 16;
  __shared__ short BL[128 * COLS];
  __shared__ float biasL[COLS];
  for (int i = threadIdx.x; i < 128 * COLS / 8; i += 256)
    ((int4*)BL)[i] = ((const int4*)Wp)[i];
  if (threadIdx.x < COLS) biasL[threadIdx.x] = bias ? bias[threadIdx.x] : 0.f;
  __syncthreads();
  int t = threadIdx.x, wid = t >> 6, lane = t & 63;
  int cg = lane >> 4;
  int ntiles = (n + 15) >> 4;
  for (int tile = blockIdx.x * 4 + wid; tile < ntiles; tile += gridDim.x * 4) {
    int r0 = tile << 4;
    int row = r0 + (lane & 15);
    const float* Xr = X + (size_t)(row < n ? row : 0) * 128;
    s16x8 A[4];
    #pragma unroll
    for (int kt = 0; kt < 4; ++kt) {
      int c0 = kt * 32 + cg * 8;
      float4 xa = *(const float4*)(Xr + c0);
      float4 xb = *(const float4*)(Xr + c0 + 4);
      s16x8 a;
      a[0]=f2bf(xa.x); a[1]=f2bf(xa.y); a[2]=f2bf(xa.z); a[3]=f2bf(xa.w);
      a[4]=f2bf(xb.x); a[5]=f2bf(xb.y); a[6]=f2bf(xb.z); a[7]=f2bf(xb.w);
      A[kt] = a;
    }
    #pragma unroll
    for (int nt = 0; nt < NT; ++nt) {
      f32x4 acc = {0.f, 0.f, 0.f, 0.f};
      #pragma unroll
      for (int kt = 0; kt < 4; ++kt) {
        s16x8 b = *(const s16x8*)&BL[((kt * NT + nt) * 64 + lane) * 8];
        acc = __builtin_amdgcn_mfma_f32_16x16x32_bf16(A[kt], b, acc, 0, 0, 0);
      }
      int ncol = nt * 16 + (lane & 15);
      float bb = biasL[ncol];
      #pragma unroll
      for (int reg = 0; reg < 4; ++reg) {
        int rr = r0 + cg * 4 + reg;
        if (rr < n) C[(size_t)rr * COLS + ncol] = acc[reg] + bb;
      }
    }
  }
}

// ---------------- EGNN edge kernel: per 64-edge tile (block), 16 edges per wave.
// pre = P[dst] + Q[src] + dist*w1r ; m = relu(pre) ; msg = m @ W2 + b2 (MFMA)
// atomicAdd msg into Xout[dst]; optional coord MLP -> atomicAdd into posout[dst].
template<bool UPDATE_POS>
__global__ __launch_bounds__(256)
void k_edge(const int* __restrict__ ei, int E_, int nE,
            const float* __restrict__ posin,
            const float* __restrict__ P, const float* __restrict__ Q,
            const float* __restrict__ w1r, const float* __restrict__ b2,
            const short* __restrict__ Wpack,
            const float* __restrict__ cw1, const float* __restrict__ cb1,
            const float* __restrict__ cw2, const float* __restrict__ cb2,
            float* __restrict__ Xout, float* __restrict__ posout) {
  __shared__ short BL[16384];          // W2 bf16 frag-packed, 32 KB
  __shared__ float w1rL[128], b2L[128];
  __shared__ int   sL[64], dL[64];
  __shared__ float distL[64];
  __shared__ float part[64][4];
  __shared__ float cw1L[128], cb1L[128], cw2L[128];

  for (int i = threadIdx.x; i < 2048; i += 256)
    ((int4*)BL)[i] = ((const int4*)Wpack)[i];
  if (threadIdx.x < 128) {
    w1rL[threadIdx.x] = w1r[threadIdx.x];
    b2L[threadIdx.x]  = b2[threadIdx.x];
    if (UPDATE_POS) {
      cw1L[threadIdx.x] = cw1[threadIdx.x];
      cb1L[threadIdx.x] = cb1[threadIdx.x];
      cw2L[threadIdx.x] = cw2[threadIdx.x];
    }
  }
  __syncthreads();

  const int* esrc = ei;
  const int* edst = ei + E_;
  int ntiles = (nE + 63) >> 6;
  int t = threadIdx.x;
  int wid = t >> 6, lane = t & 63;
  int cg = lane >> 4;

  for (int tile = blockIdx.x; tile < ntiles; tile += gridDim.x) {
    int base = tile << 6;
    int r = t & 63;
    int e = base + r;
    bool valid = e < nE;
    int src = 0, dst = 0;
    if (valid) {
      if (e < E_) { src = esrc[e]; dst = edst[e]; }
      else        { src = dst = e - E_; }
    }
    float px = posin[src*3+0] - posin[dst*3+0];
    float py = posin[src*3+1] - posin[dst*3+1];
    float pz = posin[src*3+2] - posin[dst*3+2];
    float dist = sqrtf(px*px + py*py + pz*pz + 1e-8f);

    __syncthreads();   // previous tile's LDS reads done
    if (t < 64) { sL[t] = src; dL[t] = dst; distL[t] = valid ? dist : 0.f; }
    if (UPDATE_POS) {
      int p = t >> 6;
      float ps = 0.f;
      #pragma unroll 8
      for (int j = p * 32; j < p * 32 + 32; ++j)
        ps += fmaxf(dist * cw1L[j] + cb1L[j], 0.f) * cw2L[j];
      part[r][p] = ps;
    }
    __syncthreads();

    if (UPDATE_POS && t < 64 && valid) {
      float s = part[t][0] + part[t][1] + part[t][2] + part[t][3] + cb2[0];
      atomicAdd(&posout[(size_t)dst*3+0], s * px);
      atomicAdd(&posout[(size_t)dst*3+1], s * py);
      atomicAdd(&posout[(size_t)dst*3+2], s * pz);
    }

    // MFMA phase: wave wid -> edges base + wid*16 .. +15
    int r16 = (wid << 4) + (lane & 15);
    int msrc = sL[r16], mdst = dL[r16];
    float mdist = distL[r16];
    s16x8 A[4];
    #pragma unroll
    for (int kt = 0; kt < 4; ++kt) {
      int c0 = kt * 32 + cg * 8;
      const float* Pr = P + (size_t)mdst * 128 + c0;
      const float* Qr = Q + (size_t)msrc * 128 + c0;
      float4 pa = *(const float4*)Pr;
      float4 pb = *(const float4*)(Pr + 4);
      float4 qa = *(const float4*)Qr;
      float4 qb = *(const float4*)(Qr + 4);
      float v0 = pa.x + qa.x, v1 = pa.y + qa.y, v2 = pa.z + qa.z, v3 = pa.w + qa.w;
      float v4 = pb.x + qb.x, v5 = pb.y + qb.y, v6 = pb.z + qb.z, v7 = pb.w + qb.w;
      s16x8 a;
      a[0] = f2bf(fmaxf(v0 + mdist * w1rL[c0+0], 0.f));
      a[1] = f2bf(fmaxf(v1 + mdist * w1rL[c0+1], 0.f));
      a[2] = f2bf(fmaxf(v2 + mdist * w1rL[c0+2], 0.f));
      a[3] = f2bf(fmaxf(v3 + mdist * w1rL[c0+3], 0.f));
      a[4] = f2bf(fmaxf(v4 + mdist * w1rL[c0+4], 0.f));
      a[5] = f2bf(fmaxf(v5 + mdist * w1rL[c0+5], 0.f));
      a[6] = f2bf(fmaxf(v6 + mdist * w1rL[c0+6], 0.f));
      a[7] = f2bf(fmaxf(v7 + mdist * w1rL[c0+7], 0.f));
      A[kt] = a;
    }
    #pragma unroll
    for (int nt = 0; nt < 8; ++nt) {
      f32x4 acc = {0.f, 0.f, 0.f, 0.f};
      #pragma unroll
      for (int kt = 0; kt < 4; ++kt) {
        s16x8 b = *(const s16x8*)&BL[((kt * 8 + nt) * 64 + lane) * 8];
        acc = __builtin_amdgcn_mfma_f32_16x16x32_bf16(A[kt], b, acc, 0, 0, 0);
      }
      int ncol = nt * 16 + (lane & 15);
      float bb = b2L[ncol];
      #pragma unroll
      for (int reg = 0; reg < 4; ++reg) {
        int m = cg * 4 + reg;
        int eg = base + (wid << 4) + m;
        if (eg < nE) {
          int dd = dL[(wid << 4) + m];
          atomicAdd(&Xout[(size_t)dd * 128 + ncol], acc[reg] + bb);
        }
      }
    }
  }
}

// ---------------- bond predictor edge part: logits = relu(U[src]+V[dst]) @ w2 + b2
__global__ __launch_bounds__(256)
void k_bond(const int* __restrict__ ei, int E_,
            const float* __restrict__ U, const float* __restrict__ V,
            const float* __restrict__ w2, const float* __restrict__ b2,
            float* __restrict__ out) {
  __shared__ float w2L[256];
  w2L[threadIdx.x] = w2[threadIdx.x];
  __syncthreads();
  int t = threadIdx.x;
  int lane = t & 63, wid = t >> 6;
  int sub = lane >> 4, j = lane & 15;
  int ntiles = (E_ + 15) >> 4;
  float b20 = b2[0], b21 = b2[1], b22 = b2[2], b23 = b2[3];
  for (int tile = blockIdx.x; tile < ntiles; tile += gridDim.x) {
    int e = (tile << 4) + (wid << 2) + sub;
    bool valid = e < E_;
    int s = valid ? ei[e] : 0;
    int d = valid ? ei[E_ + e] : 0;
    float4 u = *(const float4*)&U[(size_t)s * 64 + j * 4];
    float4 v = *(const float4*)&V[(size_t)d * 64 + j * 4];
    float h0 = fmaxf(u.x + v.x, 0.f), h1 = fmaxf(u.y + v.y, 0.f);
    float h2 = fmaxf(u.z + v.z, 0.f), h3 = fmaxf(u.w + v.w, 0.f);
    float lp[4];
    #pragma unroll
    for (int c = 0; c < 4; ++c)
      lp[c] = h0 * w2L[(j*4+0)*4+c] + h1 * w2L[(j*4+1)*4+c]
            + h2 * w2L[(j*4+2)*4+c] + h3 * w2L[(j*4+3)*4+c];
    #pragma unroll
    for (int m = 1; m < 16; m <<= 1) {
      #pragma unroll
      for (int c = 0; c < 4; ++c) lp[c] += __shfl_xor(lp[c], m, 64);
    }
    if (valid && j == 0) {
      float4 o = {lp[0] + b20, lp[1] + b21, lp[2] + b22, lp[3] + b23};
      *(float4*)&out[(size_t)e * 4] = o;
    }
  }
}

// ---------------- output: d_out[0..N*64) = X2[:, :64]
__global__ void k_outx(const float* __restrict__ X2, float* __restrict__ out, int n) {
  int i = blockIdx.x * 256 + threadIdx.x;   // over n*16 float4
  if (i >= n * 16) return;
  int node = i >> 4, c4 = i & 15;
  *(float4*)&out[(size_t)node * 64 + c4 * 4] = *(const float4*)&X2[(size_t)node * 128 + c4 * 4];
}

extern "C" void kernel_launch(void* const* d_in, const int* in_sizes, int n_in,
                              void* d_out, int out_size, void* d_ws, size_t ws_size,
                              hipStream_t stream) {
  const float* x_t   = (const float*)d_in[0];
  const float* pos   = (const float*)d_in[1];
  const int*   ei    = (const int*)d_in[2];
  const int*   tt    = (const int*)d_in[3];
  const float* cond  = (const float*)d_in[4];
  const float* te_w1 = (const float*)d_in[5];
  const float* te_b1 = (const float*)d_in[6];
  const float* te_w2 = (const float*)d_in[7];
  const float* te_b2 = (const float*)d_in[8];
  const float* l1_nm_w1 = (const float*)d_in[9];
  const float* l1_nm_b1 = (const float*)d_in[10];
  const float* l1_nm_w2 = (const float*)d_in[11];
  const float* l1_nm_b2 = (const float*)d_in[12];
  const float* l1_cm_w1 = (const float*)d_in[13];
  const float* l1_cm_b1 = (const float*)d_in[14];
  const float* l1_cm_w2 = (const float*)d_in[15];
  const float* l1_cm_b2 = (const float*)d_in[16];
  const float* l2_nm_w1 = (const float*)d_in[17];
  const float* l2_nm_b1 = (const float*)d_in[18];
  const float* l2_nm_w2 = (const float*)d_in[19];
  const float* l2_nm_b2 = (const float*)d_in[20];
  const float* l2_cm_w1 = (const float*)d_in[21];
  const float* l2_cm_b1 = (const float*)d_in[22];
  const float* l2_cm_w2 = (const float*)d_in[23];
  const float* l2_cm_b2 = (const float*)d_in[24];
  const float* bp_w1 = (const float*)d_in[25];
  const float* bp_b1 = (const float*)d_in[26];
  const float* bp_w2 = (const float*)d_in[27];
  const float* bp_b2 = (const float*)d_in[28];

  int n  = in_sizes[0] / 64;
  int E_ = in_sizes[2] / 2;
  int nE = E_ + n;

  uintptr_t base = (uintptr_t)d_ws;
  size_t off = 0;
  auto alloc = [&](size_t bytes) -> void* {
    void* p = (void*)(base + off);
    off += (bytes + 255) & ~(size_t)255;
    return p;
  };
  float* t_emb   = (float*)alloc(32 * 4);
  short* pk_l1_t = (short*)alloc(16384 * 2);
  short* pk_l1_m = (short*)alloc(16384 * 2);
  short* pk_l1_2 = (short*)alloc(16384 * 2);
  short* pk_l2_t = (short*)alloc(16384 * 2);
  short* pk_l2_m = (short*)alloc(16384 * 2);
  short* pk_l2_2 = (short*)alloc(16384 * 2);
  short* pk_bp_t = (short*)alloc(8192 * 2);
  short* pk_bp_b = (short*)alloc(8192 * 2);
  float* X0   = (float*)alloc((size_t)n * 128 * 4);
  float* X1   = (float*)alloc((size_t)n * 128 * 4);
  float* Pb   = (float*)alloc((size_t)n * 128 * 4);
  float* Qb   = (float*)alloc((size_t)n * 128 * 4);
  float* pos1 = (float*)alloc((size_t)n * 3 * 4);

  // packs + time embed
  k_time_embed<<<1, 64, 0, stream>>>(tt, te_w1, te_b1, te_w2, te_b2, t_emb);
  k_pack_w<128><<<64, 256, 0, stream>>>(l1_nm_w1,             pk_l1_t);
  k_pack_w<128><<<64, 256, 0, stream>>>(l1_nm_w1 + 128 * 128, pk_l1_m);
  k_pack_w<128><<<64, 256, 0, stream>>>(l1_nm_w2,             pk_l1_2);
  k_pack_w<128><<<64, 256, 0, stream>>>(l2_nm_w1,             pk_l2_t);
  k_pack_w<128><<<64, 256, 0, stream>>>(l2_nm_w1 + 128 * 128, pk_l2_m);
  k_pack_w<128><<<64, 256, 0, stream>>>(l2_nm_w2,             pk_l2_2);
  k_pack_w<64><<<32, 256, 0, stream>>>(bp_w1,            pk_bp_t);
  k_pack_w<64><<<32, 256, 0, stream>>>(bp_w1 + 128 * 64, pk_bp_b);

  k_build_xin<<<(n * 32 + 255) / 256, 256, 0, stream>>>(x_t, cond, t_emb, X0, n);

  // ---- layer 1
  k_mgemm<128><<<512, 256, 0, stream>>>(X0, pk_l1_t, l1_nm_b1, Pb, n);
  k_mgemm<128><<<512, 256, 0, stream>>>(X0, pk_l1_m, nullptr,  Qb, n);
  k_copy4<<<2048, 256, 0, stream>>>((const float4*)X0, (float4*)X1, (size_t)n * 32);
  k_copyf<<<(n * 3 + 255) / 256, 256, 0, stream>>>(pos, pos1, n * 3);
  k_edge<true><<<1024, 256, 0, stream>>>(ei, E_, nE, pos, Pb, Qb,
                                         l1_nm_w1 + 256 * 128, l1_nm_b2, pk_l1_2,
                                         l1_cm_w1, l1_cm_b1, l1_cm_w2, l1_cm_b2,
                                         X1, pos1);
  // ---- layer 2 (pos2 is dead -> skip coord path)
  k_mgemm<128><<<512, 256, 0, stream>>>(X1, pk_l2_t, l2_nm_b1, Pb, n);
  k_mgemm<128><<<512, 256, 0, stream>>>(X1, pk_l2_m, nullptr,  Qb, n);
  k_copy4<<<2048, 256, 0, stream>>>((const float4*)X1, (float4*)X0, (size_t)n * 32);
  k_edge<false><<<1024, 256, 0, stream>>>(ei, E_, nE, pos1, Pb, Qb,
                                          l2_nm_w1 + 256 * 128, l2_nm_b2, pk_l2_2,
                                          nullptr, nullptr, nullptr, nullptr,
                                          X0, nullptr);
  // ---- bond predictor (U in Pb, V in Qb)
  k_mgemm<64><<<512, 256, 0, stream>>>(X0, pk_bp_t, bp_b1,  Pb, n);
  k_mgemm<64><<<512, 256, 0, stream>>>(X0, pk_bp_b, nullptr, Qb, n);
  k_outx<<<(n * 16 + 255) / 256, 256, 0, stream>>>(X0, (float*)d_out, n);
  k_bond<<<2048, 256, 0, stream>>>(ei, E_, Pb, Qb, bp_w2, bp_b2, (float*)d_out + (size_t)n * 64);
}

// Round 2
// 509.926 us; speedup vs baseline: 1.9863x; 1.9863x over previous
//
#include <hip/hip_runtime.h>
#include <hip/hip_bf16.h>
#include <stdint.h>

typedef float  f32x4 __attribute__((ext_vector_type(4)));
typedef short  s16x8 __attribute__((ext_vector_type(8)));

__device__ __forceinline__ short f2bf(float f) {
  union { float f; unsigned u; } x; x.f = f;
  unsigned r = x.u + 0x7fffu + ((x.u >> 16) & 1u);
  return (short)(r >> 16);
}
__device__ __forceinline__ float bf2f(unsigned short u) {
  union { unsigned u; float f; } x; x.u = ((unsigned)u) << 16; return x.f;
}

// ---------------- time embedding: t/1000 -> Linear(1,32) -> ReLU -> Linear(32,32)
__global__ void k_time_embed(const int* __restrict__ t, const float* __restrict__ w1,
                             const float* __restrict__ b1, const float* __restrict__ w2,
                             const float* __restrict__ b2, float* __restrict__ out) {
  __shared__ float h[32];
  int j = threadIdx.x;
  float tin = (float)t[0] / 1000.0f;
  if (j < 32) h[j] = fmaxf(tin * w1[j] + b1[j], 0.f);
  __syncthreads();
  if (j < 32) {
    float acc = b2[j];
    for (int k = 0; k < 32; ++k) acc += h[k] * w2[k * 32 + j];
    out[j] = acc;
  }
}

// ---------------- x_input = [x_t | cond | t_embed]
__global__ void k_build_xin(const float* __restrict__ xt, const float* __restrict__ cond,
                            const float* __restrict__ temb, float* __restrict__ X, int n) {
  int i = blockIdx.x * 256 + threadIdx.x;   // over n*32 float4
  if (i >= n * 32) return;
  int node = i >> 5, c4 = i & 31;
  float4 v;
  if (c4 < 16)      v = *(const float4*)&xt[(size_t)node * 64 + c4 * 4];
  else if (c4 < 24) v = *(const float4*)&cond[(c4 - 16) * 4];
  else              v = *(const float4*)&temb[(c4 - 24) * 4];
  *(float4*)&X[(size_t)node * 128 + c4 * 4] = v;
}

// ---------------- CSR build: deg -> scan -> scatter ----------------
__global__ void k_deg_init(int* __restrict__ deg, int n) {
  int i = blockIdx.x * 256 + threadIdx.x;
  if (i < n) deg[i] = 1;                       // self loop
}
__global__ void k_deg_count(const int* __restrict__ edst, int E, int* __restrict__ deg) {
  int e = blockIdx.x * 256 + threadIdx.x;
  if (e < E) atomicAdd(&deg[edst[e]], 1);
}
// block-level inclusive scan (256/block); assumes n <= 256*256
__global__ void k_scan1(const int* __restrict__ deg, int* __restrict__ tmp,
                        int* __restrict__ bsum, int n) {
  __shared__ int sh[256];
  int i = blockIdx.x * 256 + threadIdx.x;
  int v = (i < n) ? deg[i] : 0;
  sh[threadIdx.x] = v; __syncthreads();
  for (int off = 1; off < 256; off <<= 1) {
    int t = (threadIdx.x >= off) ? sh[threadIdx.x - off] : 0;
    __syncthreads();
    sh[threadIdx.x] += t;
    __syncthreads();
  }
  if (i < n) tmp[i] = sh[threadIdx.x];
  if (threadIdx.x == 255) bsum[blockIdx.x] = sh[255];
}
__global__ void k_scan2(int* __restrict__ bsum, int nb) {
  __shared__ int sh[256];
  int t = threadIdx.x;
  int v = (t < nb) ? bsum[t] : 0;
  sh[t] = v; __syncthreads();
  for (int off = 1; off < 256; off <<= 1) {
    int u = (t >= off) ? sh[t - off] : 0;
    __syncthreads();
    sh[t] += u;
    __syncthreads();
  }
  if (t < nb) bsum[t] = sh[t] - v;            // exclusive
}
__global__ void k_scan3(const int* __restrict__ deg, const int* __restrict__ tmp,
                        const int* __restrict__ bsum, int* __restrict__ row,
                        int* __restrict__ cursor, int n) {
  int i = blockIdx.x * 256 + threadIdx.x;
  if (i < n) {
    int incl = tmp[i] + bsum[i >> 8];
    row[i + 1] = incl;
    cursor[i]  = incl - deg[i];
    if (i == 0) row[0] = 0;
  }
}
__global__ void k_scatter(const int* __restrict__ ei, int E, int nE,
                          int* __restrict__ cursor, int* __restrict__ csr_src) {
  int e = blockIdx.x * 256 + threadIdx.x;
  if (e >= nE) return;
  int s, d;
  if (e < E) { s = ei[e]; d = ei[E + e]; }
  else       { s = d = e - E; }
  int slot = atomicAdd(&cursor[d], 1);
  csr_src[slot] = s;
}

// ---------------- pack a [128][COLS] f32 weight into bf16 MFMA B-fragment layout
template<int COLS>
__global__ void k_pack_w(const float* __restrict__ W, short* __restrict__ out) {
  const int NT = COLS / 16;
  int i = blockIdx.x * 256 + threadIdx.x;
  if (i >= 128 * COLS) return;
  int j = i & 7, l = (i >> 3) & 63;
  int nt = (i >> 9) % NT;
  int kt = (i >> 9) / NT;
  int k = kt * 32 + ((l >> 4) * 8) + j;
  int ncol = nt * 16 + (l & 15);
  out[i] = f2bf(W[(size_t)k * COLS + ncol]);
}

// ---------------- node GEMM via MFMA: C = [resid +] bf16(A[n][128]) @ Wp [+ (degf*)bias]
template<int COLS, bool BF16OUT>
__global__ __launch_bounds__(256)
void k_mgemm(const float* __restrict__ X, const short* __restrict__ Wp,
             const float* __restrict__ bias, const float* __restrict__ resid,
             const float* __restrict__ degf,
             float* __restrict__ Cf, unsigned short* __restrict__ Cb, int n) {
  const int NT = COLS / 16;
  __shared__ short BL[128 * COLS];
  __shared__ float biasL[COLS];
  for (int i = threadIdx.x; i < 128 * COLS / 8; i += 256)
    ((int4*)BL)[i] = ((const int4*)Wp)[i];
  if (threadIdx.x < COLS) biasL[threadIdx.x] = bias ? bias[threadIdx.x] : 0.f;
  __syncthreads();
  int t = threadIdx.x, wid = t >> 6, lane = t & 63;
  int cg = lane >> 4;
  int ntiles = (n + 15) >> 4;
  for (int tile = blockIdx.x * 4 + wid; tile < ntiles; tile += gridDim.x * 4) {
    int r0 = tile << 4;
    int arow = r0 + (lane & 15);
    const float* Xr = X + (size_t)(arow < n ? arow : 0) * 128;
    s16x8 A[4];
    #pragma unroll
    for (int kt = 0; kt < 4; ++kt) {
      int c0 = kt * 32 + cg * 8;
      float4 xa = *(const float4*)(Xr + c0);
      float4 xb = *(const float4*)(Xr + c0 + 4);
      s16x8 a;
      a[0]=f2bf(xa.x); a[1]=f2bf(xa.y); a[2]=f2bf(xa.z); a[3]=f2bf(xa.w);
      a[4]=f2bf(xb.x); a[5]=f2bf(xb.y); a[6]=f2bf(xb.z); a[7]=f2bf(xb.w);
      A[kt] = a;
    }
    float dsc[4];
    #pragma unroll
    for (int reg = 0; reg < 4; ++reg) {
      int rr = r0 + cg * 4 + reg;
      dsc[reg] = degf ? degf[rr < n ? rr : 0] : 1.f;
    }
    #pragma unroll
    for (int nt = 0; nt < NT; ++nt) {
      f32x4 acc = {0.f, 0.f, 0.f, 0.f};
      #pragma unroll
      for (int kt = 0; kt < 4; ++kt) {
        s16x8 b = *(const s16x8*)&BL[((kt * NT + nt) * 64 + lane) * 8];
        acc = __builtin_amdgcn_mfma_f32_16x16x32_bf16(A[kt], b, acc, 0, 0, 0);
      }
      int ncol = nt * 16 + (lane & 15);
      float bb = biasL[ncol];
      #pragma unroll
      for (int reg = 0; reg < 4; ++reg) {
        int rr = r0 + cg * 4 + reg;
        if (rr < n) {
          float v = acc[reg] + dsc[reg] * bb;
          if (resid) v += resid[(size_t)rr * COLS + ncol];
          if (BF16OUT) Cb[(size_t)rr * COLS + ncol] = (unsigned short)f2bf(v);
          else         Cf[(size_t)rr * COLS + ncol] = v;
        }
      }
    }
  }
}

// ---------------- per-dst segment aggregation: one wave per node.
// S[i][:] = sum over edges (src->i) of relu(P[i] + Q[src] + dist*w1r)
// L1: also coord MLP -> pos_out[i] = pos_in[i] + sum sc*edge_vec; degf[i] = deg.
template<bool L1>
__global__ __launch_bounds__(256)
void k_aggregate(const int* __restrict__ row, const int* __restrict__ csr_src,
                 const unsigned short* __restrict__ Pb, const unsigned short* __restrict__ Qb,
                 const float* __restrict__ posin, const float* __restrict__ w1r,
                 const float* __restrict__ cw1, const float* __restrict__ cb1,
                 const float* __restrict__ cw2, const float* __restrict__ cb2,
                 float* __restrict__ S, float* __restrict__ posout,
                 float* __restrict__ degf, int n) {
  int gw = (blockIdx.x * 256 + threadIdx.x) >> 6;
  if (gw >= n) return;
  int lane = threadIdx.x & 63;
  int i = gw;
  int r0 = row[i], r1 = row[i + 1];
  ushort2 pu = *(const ushort2*)&Pb[(size_t)i * 128 + lane * 2];
  float p0 = bf2f(pu.x), p1 = bf2f(pu.y);
  float w0 = w1r[lane * 2], w1 = w1r[lane * 2 + 1];
  float pix = posin[i * 3 + 0], piy = posin[i * 3 + 1], piz = posin[i * 3 + 2];
  float a0 = 0.f, a1 = 0.f;
  float pxa = 0.f, pya = 0.f, pza = 0.f;
  float c1a = 0, c1b = 0, b1a = 0, b1b = 0, c2a = 0, c2b = 0, cb2v = 0;
  if (L1) {
    c1a = cw1[lane * 2]; c1b = cw1[lane * 2 + 1];
    b1a = cb1[lane * 2]; b1b = cb1[lane * 2 + 1];
    c2a = cw2[lane * 2]; c2b = cw2[lane * 2 + 1];
    cb2v = cb2[0];
  }
  for (int k = r0; k < r1; ++k) {
    int s = __builtin_amdgcn_readfirstlane(csr_src[k]);
    float dx = posin[s * 3 + 0] - pix;
    float dy = posin[s * 3 + 1] - piy;
    float dz = posin[s * 3 + 2] - piz;
    float dist = sqrtf(dx * dx + dy * dy + dz * dz + 1e-8f);
    ushort2 qu = *(const ushort2*)&Qb[(size_t)s * 128 + lane * 2];
    a0 += fmaxf(p0 + bf2f(qu.x) + dist * w0, 0.f);
    a1 += fmaxf(p1 + bf2f(qu.y) + dist * w1, 0.f);
    if (L1) {
      float h = fmaxf(fmaf(dist, c1a, b1a), 0.f) * c2a
              + fmaxf(fmaf(dist, c1b, b1b), 0.f) * c2b;
      #pragma unroll
      for (int m = 1; m < 64; m <<= 1) h += __shfl_xor(h, m, 64);
      float sc = h + cb2v;
      pxa = fmaf(sc, dx, pxa); pya = fmaf(sc, dy, pya); pza = fmaf(sc, dz, pza);
    }
  }
  float2 sv = {a0, a1};
  *(float2*)&S[(size_t)i * 128 + lane * 2] = sv;
  if (L1 && lane == 0) {
    posout[i * 3 + 0] = pix + pxa;
    posout[i * 3 + 1] = piy + pya;
    posout[i * 3 + 2] = piz + pza;
    degf[i] = (float)(r1 - r0);
  }
}

// ---------------- bond predictor edge part: logits = relu(U[src]+V[dst]) @ w2 + b2
__global__ __launch_bounds__(256)
void k_bond(const int* __restrict__ ei, int E_,
            const float* __restrict__ U, const float* __restrict__ V,
            const float* __restrict__ w2, const float* __restrict__ b2,
            float* __restrict__ out) {
  __shared__ float w2L[256];
  w2L[threadIdx.x] = w2[threadIdx.x];
  __syncthreads();
  int t = threadIdx.x;
  int lane = t & 63, wid = t >> 6;
  int sub = lane >> 4, j = lane & 15;
  int ntiles = (E_ + 15) >> 4;
  float b20 = b2[0], b21 = b2[1], b22 = b2[2], b23 = b2[3];
  for (int tile = blockIdx.x; tile < ntiles; tile += gridDim.x) {
    int e = (tile << 4) + (wid << 2) + sub;
    bool valid = e < E_;
    int s = valid ? ei[e] : 0;
    int d = valid ? ei[E_ + e] : 0;
    float4 u = *(const float4*)&U[(size_t)s * 64 + j * 4];
    float4 v = *(const float4*)&V[(size_t)d * 64 + j * 4];
    float h0 = fmaxf(u.x + v.x, 0.f), h1 = fmaxf(u.y + v.y, 0.f);
    float h2 = fmaxf(u.z + v.z, 0.f), h3 = fmaxf(u.w + v.w, 0.f);
    float lp[4];
    #pragma unroll
    for (int c = 0; c < 4; ++c)
      lp[c] = h0 * w2L[(j*4+0)*4+c] + h1 * w2L[(j*4+1)*4+c]
            + h2 * w2L[(j*4+2)*4+c] + h3 * w2L[(j*4+3)*4+c];
    #pragma unroll
    for (int m = 1; m < 16; m <<= 1) {
      #pragma unroll
      for (int c = 0; c < 4; ++c) lp[c] += __shfl_xor(lp[c], m, 64);
    }
    if (valid && j == 0) {
      float4 o = {lp[0] + b20, lp[1] + b21, lp[2] + b22, lp[3] + b23};
      *(float4*)&out[(size_t)e * 4] = o;
    }
  }
}

// ---------------- output: d_out[0..N*64) = X2[:, :64]
__global__ void k_outx(const float* __restrict__ X2, float* __restrict__ out, int n) {
  int i = blockIdx.x * 256 + threadIdx.x;   // over n*16 float4
  if (i >= n * 16) return;
  int node = i >> 4, c4 = i & 15;
  *(float4*)&out[(size_t)node * 64 + c4 * 4] = *(const float4*)&X2[(size_t)node * 128 + c4 * 4];
}

extern "C" void kernel_launch(void* const* d_in, const int* in_sizes, int n_in,
                              void* d_out, int out_size, void* d_ws, size_t ws_size,
                              hipStream_t stream) {
  const float* x_t   = (const float*)d_in[0];
  const float* pos   = (const float*)d_in[1];
  const int*   ei    = (const int*)d_in[2];
  const int*   tt    = (const int*)d_in[3];
  const float* cond  = (const float*)d_in[4];
  const float* te_w1 = (const float*)d_in[5];
  const float* te_b1 = (const float*)d_in[6];
  const float* te_w2 = (const float*)d_in[7];
  const float* te_b2 = (const float*)d_in[8];
  const float* l1_nm_w1 = (const float*)d_in[9];
  const float* l1_nm_b1 = (const float*)d_in[10];
  const float* l1_nm_w2 = (const float*)d_in[11];
  const float* l1_nm_b2 = (const float*)d_in[12];
  const float* l1_cm_w1 = (const float*)d_in[13];
  const float* l1_cm_b1 = (const float*)d_in[14];
  const float* l1_cm_w2 = (const float*)d_in[15];
  const float* l1_cm_b2 = (const float*)d_in[16];
  const float* l2_nm_w1 = (const float*)d_in[17];
  const float* l2_nm_b1 = (const float*)d_in[18];
  const float* l2_nm_w2 = (const float*)d_in[19];
  const float* l2_nm_b2 = (const float*)d_in[20];
  const float* bp_w1 = (const float*)d_in[25];
  const float* bp_b1 = (const float*)d_in[26];
  const float* bp_w2 = (const float*)d_in[27];
  const float* bp_b2 = (const float*)d_in[28];

  int n  = in_sizes[0] / 64;
  int E_ = in_sizes[2] / 2;
  int nE = E_ + n;
  int nb = (n + 255) / 256;

  uintptr_t base = (uintptr_t)d_ws;
  size_t off = 0;
  auto alloc = [&](size_t bytes) -> void* {
    void* p = (void*)(base + off);
    off += (bytes + 255) & ~(size_t)255;
    return p;
  };
  float* t_emb   = (float*)alloc(32 * 4);
  short* pk_l1_t = (short*)alloc(16384 * 2);
  short* pk_l1_m = (short*)alloc(16384 * 2);
  short* pk_l1_2 = (short*)alloc(16384 * 2);
  short* pk_l2_t = (short*)alloc(16384 * 2);
  short* pk_l2_m = (short*)alloc(16384 * 2);
  short* pk_l2_2 = (short*)alloc(16384 * 2);
  short* pk_bp_t = (short*)alloc(8192 * 2);
  short* pk_bp_b = (short*)alloc(8192 * 2);
  float* X0   = (float*)alloc((size_t)n * 128 * 4);
  float* X1   = (float*)alloc((size_t)n * 128 * 4);
  float* S    = (float*)alloc((size_t)n * 128 * 4);   // also U|V later
  unsigned short* Pbf = (unsigned short*)alloc((size_t)n * 128 * 2);
  unsigned short* Qbf = (unsigned short*)alloc((size_t)n * 128 * 2);
  int*   deg    = (int*)alloc((size_t)n * 4);
  int*   tmp    = (int*)alloc((size_t)n * 4);
  int*   bsum   = (int*)alloc(256 * 4);
  int*   rowp   = (int*)alloc(((size_t)n + 1) * 4);
  int*   cursor = (int*)alloc((size_t)n * 4);
  int*   csrsrc = (int*)alloc((size_t)nE * 4);
  float* degf   = (float*)alloc((size_t)n * 4);
  float* pos1   = (float*)alloc((size_t)n * 3 * 4);
  float* U = S;
  float* V = S + (size_t)n * 64;

  // constants / packs / input assembly
  k_time_embed<<<1, 64, 0, stream>>>(tt, te_w1, te_b1, te_w2, te_b2, t_emb);
  k_pack_w<128><<<64, 256, 0, stream>>>(l1_nm_w1,             pk_l1_t);
  k_pack_w<128><<<64, 256, 0, stream>>>(l1_nm_w1 + 128 * 128, pk_l1_m);
  k_pack_w<128><<<64, 256, 0, stream>>>(l1_nm_w2,             pk_l1_2);
  k_pack_w<128><<<64, 256, 0, stream>>>(l2_nm_w1,             pk_l2_t);
  k_pack_w<128><<<64, 256, 0, stream>>>(l2_nm_w1 + 128 * 128, pk_l2_m);
  k_pack_w<128><<<64, 256, 0, stream>>>(l2_nm_w2,             pk_l2_2);
  k_pack_w<64><<<32, 256, 0, stream>>>(bp_w1,            pk_bp_t);
  k_pack_w<64><<<32, 256, 0, stream>>>(bp_w1 + 128 * 64, pk_bp_b);
  k_build_xin<<<(n * 32 + 255) / 256, 256, 0, stream>>>(x_t, cond, t_emb, X0, n);

  // CSR by dst (shared by both layers)
  k_deg_init<<<nb, 256, 0, stream>>>(deg, n);
  k_deg_count<<<(E_ + 255) / 256, 256, 0, stream>>>(ei + E_, E_, deg);
  k_scan1<<<nb, 256, 0, stream>>>(deg, tmp, bsum, n);
  k_scan2<<<1, 256, 0, stream>>>(bsum, nb);
  k_scan3<<<nb, 256, 0, stream>>>(deg, tmp, bsum, rowp, cursor, n);
  k_scatter<<<(nE + 255) / 256, 256, 0, stream>>>(ei, E_, nE, cursor, csrsrc);

  // ---- layer 1
  k_mgemm<128,true><<<512, 256, 0, stream>>>(X0, pk_l1_t, l1_nm_b1, nullptr, nullptr, nullptr, Pbf, n);
  k_mgemm<128,true><<<512, 256, 0, stream>>>(X0, pk_l1_m, nullptr,  nullptr, nullptr, nullptr, Qbf, n);
  k_aggregate<true><<<(n + 3) / 4, 256, 0, stream>>>(rowp, csrsrc, Pbf, Qbf, pos,
      l1_nm_w1 + 256 * 128, l1_cm_w1, l1_cm_b1, l1_cm_w2, l1_cm_b2, S, pos1, degf, n);
  k_mgemm<128,false><<<512, 256, 0, stream>>>(S, pk_l1_2, l1_nm_b2, X0, degf, X1, nullptr, n);

  // ---- layer 2 (pos2 dead -> no coord path)
  k_mgemm<128,true><<<512, 256, 0, stream>>>(X1, pk_l2_t, l2_nm_b1, nullptr, nullptr, nullptr, Pbf, n);
  k_mgemm<128,true><<<512, 256, 0, stream>>>(X1, pk_l2_m, nullptr,  nullptr, nullptr, nullptr, Qbf, n);
  k_aggregate<false><<<(n + 3) / 4, 256, 0, stream>>>(rowp, csrsrc, Pbf, Qbf, pos1,
      l2_nm_w1 + 256 * 128, nullptr, nullptr, nullptr, nullptr, S, nullptr, nullptr, n);
  k_mgemm<128,false><<<512, 256, 0, stream>>>(S, pk_l2_2, l2_nm_b2, X1, degf, X0, nullptr, n);

  // ---- bond predictor (U,V live in S buffer; X2 == X0)
  k_mgemm<64,false><<<512, 256, 0, stream>>>(X0, pk_bp_t, bp_b1,  nullptr, nullptr, U, nullptr, n);
  k_mgemm<64,false><<<512, 256, 0, stream>>>(X0, pk_bp_b, nullptr, nullptr, nullptr, V, nullptr, n);
  k_outx<<<(n * 16 + 255) / 256, 256, 0, stream>>>(X0, (float*)d_out, n);
  k_bond<<<2048, 256, 0, stream>>>(ei, E_, U, V, bp_w2, bp_b2, (float*)d_out + (size_t)n * 64);
}

// Round 3
// 431.362 us; speedup vs baseline: 2.3480x; 1.1821x over previous
//
#include <hip/hip_runtime.h>
#include <hip/hip_bf16.h>
#include <stdint.h>

typedef float  f32x4 __attribute__((ext_vector_type(4)));
typedef short  s16x8 __attribute__((ext_vector_type(8)));
typedef unsigned short ushort_t;

__device__ __forceinline__ short f2bf(float f) {
  union { float f; unsigned u; } x; x.f = f;
  unsigned r = x.u + 0x7fffu + ((x.u >> 16) & 1u);
  return (short)(r >> 16);
}
__device__ __forceinline__ float bf2f(unsigned short u) {
  union { unsigned u; float f; } x; x.u = ((unsigned)u) << 16; return x.f;
}

// ---------------- time embedding
__global__ void k_time_embed(const int* __restrict__ t, const float* __restrict__ w1,
                             const float* __restrict__ b1, const float* __restrict__ w2,
                             const float* __restrict__ b2, float* __restrict__ out) {
  __shared__ float h[32];
  int j = threadIdx.x;
  float tin = (float)t[0] / 1000.0f;
  if (j < 32) h[j] = fmaxf(tin * w1[j] + b1[j], 0.f);
  __syncthreads();
  if (j < 32) {
    float acc = b2[j];
    for (int k = 0; k < 32; ++k) acc += h[k] * w2[k * 32 + j];
    out[j] = acc;
  }
}

// ---------------- x_input = [x_t | cond | t_embed]
__global__ void k_build_xin(const float* __restrict__ xt, const float* __restrict__ cond,
                            const float* __restrict__ temb, float* __restrict__ X, int n) {
  int i = blockIdx.x * 256 + threadIdx.x;
  if (i >= n * 32) return;
  int node = i >> 5, c4 = i & 31;
  float4 v;
  if (c4 < 16)      v = *(const float4*)&xt[(size_t)node * 64 + c4 * 4];
  else if (c4 < 24) v = *(const float4*)&cond[(c4 - 16) * 4];
  else              v = *(const float4*)&temb[(c4 - 24) * 4];
  *(float4*)&X[(size_t)node * 128 + c4 * 4] = v;
}

// ---------------- CSR build ----------------
__global__ void k_deg_init(int* __restrict__ deg, int n) {
  int i = blockIdx.x * 256 + threadIdx.x;
  if (i < n) deg[i] = 1;
}
__global__ void k_deg_count(const int* __restrict__ edst, int E, int* __restrict__ deg) {
  int e = blockIdx.x * 256 + threadIdx.x;
  if (e < E) atomicAdd(&deg[edst[e]], 1);
}
__global__ void k_scan1(const int* __restrict__ deg, int* __restrict__ tmp,
                        int* __restrict__ bsum, int n) {
  __shared__ int sh[256];
  int i = blockIdx.x * 256 + threadIdx.x;
  int v = (i < n) ? deg[i] : 0;
  sh[threadIdx.x] = v; __syncthreads();
  for (int off = 1; off < 256; off <<= 1) {
    int t = (threadIdx.x >= off) ? sh[threadIdx.x - off] : 0;
    __syncthreads();
    sh[threadIdx.x] += t;
    __syncthreads();
  }
  if (i < n) tmp[i] = sh[threadIdx.x];
  if (threadIdx.x == 255) bsum[blockIdx.x] = sh[255];
}
__global__ void k_scan2(int* __restrict__ bsum, int nb) {
  __shared__ int sh[256];
  int t = threadIdx.x;
  int v = (t < nb) ? bsum[t] : 0;
  sh[t] = v; __syncthreads();
  for (int off = 1; off < 256; off <<= 1) {
    int u = (t >= off) ? sh[t - off] : 0;
    __syncthreads();
    sh[t] += u;
    __syncthreads();
  }
  if (t < nb) bsum[t] = sh[t] - v;
}
__global__ void k_scan3(const int* __restrict__ deg, const int* __restrict__ tmp,
                        const int* __restrict__ bsum, int* __restrict__ row,
                        int* __restrict__ cursor, int n) {
  int i = blockIdx.x * 256 + threadIdx.x;
  if (i < n) {
    int incl = tmp[i] + bsum[i >> 8];
    row[i + 1] = incl;
    cursor[i]  = incl - deg[i];
    if (i == 0) row[0] = 0;
  }
}
__global__ void k_scatter(const int* __restrict__ ei, int E, int nE,
                          int* __restrict__ cursor, int* __restrict__ csr_src,
                          int* __restrict__ csr_dst) {
  int e = blockIdx.x * 256 + threadIdx.x;
  if (e >= nE) return;
  int s, d;
  if (e < E) { s = ei[e]; d = ei[E + e]; }
  else       { s = d = e - E; }
  int slot = atomicAdd(&cursor[d], 1);
  csr_src[slot] = s;
  csr_dst[slot] = d;
}

// ---------------- merged weight pack (8 regions) into bf16 MFMA B-frag layout
__device__ __forceinline__ void pack_one(const float* W, int cols, int local, short* dst) {
  int NT = cols / 16;
  int j = local & 7, l = (local >> 3) & 63;
  int nt = (local >> 9) % NT;
  int kt = (local >> 9) / NT;
  int k = kt * 32 + ((l >> 4) * 8) + j;
  int ncol = nt * 16 + (l & 15);
  dst[local] = f2bf(W[(size_t)k * cols + ncol]);
}
__global__ void k_pack_all(const float* __restrict__ w0, const float* __restrict__ w1,
                           const float* __restrict__ w2, const float* __restrict__ w3,
                           const float* __restrict__ w4, const float* __restrict__ w5,
                           const float* __restrict__ w6, const float* __restrict__ w7,
                           short* __restrict__ out) {
  int i = blockIdx.x * 256 + threadIdx.x;
  if (i >= 114688) return;
  if (i < 98304) {
    int r = i >> 14, local = i & 16383;
    const float* W = r == 0 ? w0 : r == 1 ? w1 : r == 2 ? w2 : r == 3 ? w3 : r == 4 ? w4 : w5;
    pack_one(W, 128, local, out + r * 16384);
  } else {
    int j = i - 98304;
    int r = j >> 13, local = j & 8191;
    pack_one(r ? w7 : w6, 64, local, out + 98304 + r * 8192);
  }
}

// ---------------- generic node GEMM via MFMA
// out[n][COLS] = A[n][128] @ Wp (+ degf*bias) (+ resid); A f32 or bf16; out f32 or bf16
// optional out64: also write first 64 cols as f32 (final-layer fusion)
template<int COLS, bool ABF16, bool OUTBF16>
__global__ __launch_bounds__(256)
void k_mgemm(const void* __restrict__ A, const short* __restrict__ Wp,
             const float* __restrict__ bias, const float* __restrict__ resid,
             const float* __restrict__ degf, void* __restrict__ out,
             float* __restrict__ out64, int n) {
  const int NT = COLS / 16;
  __shared__ short BL[128 * COLS];
  for (int i = threadIdx.x; i < 128 * COLS / 8; i += 256)
    ((int4*)BL)[i] = ((const int4*)Wp)[i];
  __syncthreads();
  int t = threadIdx.x, wid = t >> 6, lane = t & 63;
  int cg = lane >> 4;
  float bb[NT];
  #pragma unroll
  for (int nt = 0; nt < NT; ++nt)
    bb[nt] = bias ? bias[nt * 16 + (lane & 15)] : 0.f;
  int ntiles = (n + 15) >> 4;
  for (int tile = blockIdx.x * 4 + wid; tile < ntiles; tile += gridDim.x * 4) {
    int r0 = tile << 4;
    int arow = r0 + (lane & 15);
    int crow = arow < n ? arow : 0;
    s16x8 Af[4];
    if (ABF16) {
      const ushort_t* Ar = (const ushort_t*)A + (size_t)crow * 128;
      #pragma unroll
      for (int kt = 0; kt < 4; ++kt)
        Af[kt] = *(const s16x8*)(Ar + kt * 32 + cg * 8);
    } else {
      const float* Ar = (const float*)A + (size_t)crow * 128;
      #pragma unroll
      for (int kt = 0; kt < 4; ++kt) {
        int c0 = kt * 32 + cg * 8;
        float4 xa = *(const float4*)(Ar + c0);
        float4 xb = *(const float4*)(Ar + c0 + 4);
        s16x8 a;
        a[0]=f2bf(xa.x); a[1]=f2bf(xa.y); a[2]=f2bf(xa.z); a[3]=f2bf(xa.w);
        a[4]=f2bf(xb.x); a[5]=f2bf(xb.y); a[6]=f2bf(xb.z); a[7]=f2bf(xb.w);
        Af[kt] = a;
      }
    }
    float dsc[4];
    #pragma unroll
    for (int reg = 0; reg < 4; ++reg) {
      int rr = r0 + cg * 4 + reg;
      dsc[reg] = degf ? degf[rr < n ? rr : 0] : 1.f;
    }
    #pragma unroll
    for (int nt = 0; nt < NT; ++nt) {
      f32x4 acc = {0.f, 0.f, 0.f, 0.f};
      #pragma unroll
      for (int kt = 0; kt < 4; ++kt) {
        s16x8 b = *(const s16x8*)&BL[((kt * NT + nt) * 64 + lane) * 8];
        acc = __builtin_amdgcn_mfma_f32_16x16x32_bf16(Af[kt], b, acc, 0, 0, 0);
      }
      int ncol = nt * 16 + (lane & 15);
      #pragma unroll
      for (int reg = 0; reg < 4; ++reg) {
        int rr = r0 + cg * 4 + reg;
        if (rr < n) {
          float v = acc[reg] + dsc[reg] * bb[nt];
          if (resid) v += resid[(size_t)rr * COLS + ncol];
          if (OUTBF16) ((ushort_t*)out)[(size_t)rr * COLS + ncol] = (ushort_t)f2bf(v);
          else         ((float*)out)[(size_t)rr * COLS + ncol] = v;
          if (out64 && ncol < 64) out64[(size_t)rr * 64 + ncol] = v;
        }
      }
    }
  }
}

// ---------------- per-edge aux (CSR-slot order), layer 1: dist + coord-MLP * edge_vec
__global__ __launch_bounds__(256)
void k_aux1(const int* __restrict__ csr_src, const int* __restrict__ csr_dst, int nE,
            const float* __restrict__ pos,
            const float* __restrict__ cw1, const float* __restrict__ cb1,
            const float* __restrict__ cw2, const float* __restrict__ cb2,
            float4* __restrict__ aux) {
  int k = blockIdx.x * 256 + threadIdx.x;
  if (k >= nE) return;
  int s = csr_src[k], d = csr_dst[k];
  float dx = pos[s*3+0] - pos[d*3+0];
  float dy = pos[s*3+1] - pos[d*3+1];
  float dz = pos[s*3+2] - pos[d*3+2];
  float dist = sqrtf(dx*dx + dy*dy + dz*dz + 1e-8f);
  float h = cb2[0];
  #pragma unroll 4
  for (int j = 0; j < 128; ++j)
    h += fmaxf(fmaf(dist, cw1[j], cb1[j]), 0.f) * cw2[j];
  float4 o; o.x = dist; o.y = h * dx; o.z = h * dy; o.w = h * dz;
  aux[k] = o;
}

// ---------------- per-edge aux, layer 2: dist only
__global__ __launch_bounds__(256)
void k_aux2(const int* __restrict__ csr_src, const int* __restrict__ csr_dst, int nE,
            const float* __restrict__ pos, float* __restrict__ auxd) {
  int k = blockIdx.x * 256 + threadIdx.x;
  if (k >= nE) return;
  int s = csr_src[k], d = csr_dst[k];
  float dx = pos[s*3+0] - pos[d*3+0];
  float dy = pos[s*3+1] - pos[d*3+1];
  float dz = pos[s*3+2] - pos[d*3+2];
  auxd[k] = sqrtf(dx*dx + dy*dy + dz*dz + 1e-8f);
}

// ---------------- per-dst aggregation: one wave per node, software-pipelined.
// Sb[i][:] (bf16) = sum over src of relu(P[i] + Q[src] + dist*w1r)
// L1: posout[i] = posin[i] + sum(sc*edge_vec); degf[i] = deg
template<bool L1>
__global__ __launch_bounds__(256)
void k_aggregate(const int* __restrict__ row, const int* __restrict__ csr_src,
                 const float4* __restrict__ aux4, const float* __restrict__ auxd,
                 const ushort_t* __restrict__ Pb, const ushort_t* __restrict__ Qb,
                 const float* __restrict__ w1r,
                 const float* __restrict__ posin, float* __restrict__ posout,
                 float* __restrict__ degf, ushort_t* __restrict__ Sb, int n) {
  int gw = (blockIdx.x * 256 + threadIdx.x) >> 6;
  if (gw >= n) return;
  int lane = threadIdx.x & 63;
  int r0 = row[gw], r1 = row[gw + 1];
  ushort2 pu = *(const ushort2*)&Pb[(size_t)gw * 128 + (lane << 1)];
  float p0 = bf2f(pu.x), p1 = bf2f(pu.y);
  float w0 = w1r[lane * 2], w1 = w1r[lane * 2 + 1];
  float a0 = 0.f, a1 = 0.f, pacc = 0.f;

  // pipeline: stage k's loads issued one iteration ahead
  int sA = csr_src[r0];
  float4 axA;
  if (L1) axA = aux4[r0]; else { axA.x = auxd[r0]; axA.y = axA.z = axA.w = 0.f; }
  ushort2 qA = *(const ushort2*)&Qb[(size_t)sA * 128 + (lane << 1)];
  for (int k = r0 + 1; k < r1; ++k) {
    int sB = csr_src[k];
    float4 axB;
    if (L1) axB = aux4[k]; else { axB.x = auxd[k]; axB.y = axB.z = axB.w = 0.f; }
    ushort2 qB = *(const ushort2*)&Qb[(size_t)sB * 128 + (lane << 1)];
    a0 += fmaxf(fmaf(axA.x, w0, p0 + bf2f(qA.x)), 0.f);
    a1 += fmaxf(fmaf(axA.x, w1, p1 + bf2f(qA.y)), 0.f);
    if (L1 && lane < 3) pacc += (lane == 0) ? axA.y : (lane == 1) ? axA.z : axA.w;
    qA = qB; axA = axB;
  }
  a0 += fmaxf(fmaf(axA.x, w0, p0 + bf2f(qA.x)), 0.f);
  a1 += fmaxf(fmaf(axA.x, w1, p1 + bf2f(qA.y)), 0.f);
  if (L1 && lane < 3) pacc += (lane == 0) ? axA.y : (lane == 1) ? axA.z : axA.w;

  ushort2 o; o.x = (ushort_t)f2bf(a0); o.y = (ushort_t)f2bf(a1);
  *(ushort2*)&Sb[(size_t)gw * 128 + (lane << 1)] = o;
  if (L1) {
    if (lane < 3) posout[gw * 3 + lane] = posin[gw * 3 + lane] + pacc;
    if (lane == 0) degf[gw] = (float)(r1 - r0);
  }
}

// ---------------- bond predictor: logits = relu(U[src]+V[dst]) @ w2 + b2 (bf16 U,V)
__global__ __launch_bounds__(256)
void k_bond(const int* __restrict__ ei, int E_,
            const ushort_t* __restrict__ U, const ushort_t* __restrict__ V,
            const float* __restrict__ w2, const float* __restrict__ b2,
            float* __restrict__ out) {
  __shared__ float w2L[256];
  w2L[threadIdx.x] = w2[threadIdx.x];
  __syncthreads();
  int gid = blockIdx.x * 256 + threadIdx.x;
  int e = gid >> 4;
  if (e >= E_) return;
  int j = threadIdx.x & 15;
  int s = ei[e];
  int d = ei[E_ + e];
  ushort4 u4 = *(const ushort4*)&U[(size_t)s * 64 + j * 4];
  ushort4 v4 = *(const ushort4*)&V[(size_t)d * 64 + j * 4];
  float h0 = fmaxf(bf2f(u4.x) + bf2f(v4.x), 0.f);
  float h1 = fmaxf(bf2f(u4.y) + bf2f(v4.y), 0.f);
  float h2 = fmaxf(bf2f(u4.z) + bf2f(v4.z), 0.f);
  float h3 = fmaxf(bf2f(u4.w) + bf2f(v4.w), 0.f);
  float lp[4];
  #pragma unroll
  for (int c = 0; c < 4; ++c)
    lp[c] = h0 * w2L[(j*4+0)*4+c] + h1 * w2L[(j*4+1)*4+c]
          + h2 * w2L[(j*4+2)*4+c] + h3 * w2L[(j*4+3)*4+c];
  #pragma unroll
  for (int m = 1; m < 16; m <<= 1) {
    #pragma unroll
    for (int c = 0; c < 4; ++c) lp[c] += __shfl_xor(lp[c], m, 64);
  }
  if (j == 0) {
    float4 o = {lp[0] + b2[0], lp[1] + b2[1], lp[2] + b2[2], lp[3] + b2[3]};
    *(float4*)&out[(size_t)e * 4] = o;
  }
}

extern "C" void kernel_launch(void* const* d_in, const int* in_sizes, int n_in,
                              void* d_out, int out_size, void* d_ws, size_t ws_size,
                              hipStream_t stream) {
  const float* x_t   = (const float*)d_in[0];
  const float* pos   = (const float*)d_in[1];
  const int*   ei    = (const int*)d_in[2];
  const int*   tt    = (const int*)d_in[3];
  const float* cond  = (const float*)d_in[4];
  const float* te_w1 = (const float*)d_in[5];
  const float* te_b1 = (const float*)d_in[6];
  const float* te_w2 = (const float*)d_in[7];
  const float* te_b2 = (const float*)d_in[8];
  const float* l1_nm_w1 = (const float*)d_in[9];
  const float* l1_nm_b1 = (const float*)d_in[10];
  const float* l1_nm_w2 = (const float*)d_in[11];
  const float* l1_nm_b2 = (const float*)d_in[12];
  const float* l1_cm_w1 = (const float*)d_in[13];
  const float* l1_cm_b1 = (const float*)d_in[14];
  const float* l1_cm_w2 = (const float*)d_in[15];
  const float* l1_cm_b2 = (const float*)d_in[16];
  const float* l2_nm_w1 = (const float*)d_in[17];
  const float* l2_nm_b1 = (const float*)d_in[18];
  const float* l2_nm_w2 = (const float*)d_in[19];
  const float* l2_nm_b2 = (const float*)d_in[20];
  const float* bp_w1 = (const float*)d_in[25];
  const float* bp_b1 = (const float*)d_in[26];
  const float* bp_w2 = (const float*)d_in[27];
  const float* bp_b2 = (const float*)d_in[28];

  int n  = in_sizes[0] / 64;
  int E_ = in_sizes[2] / 2;
  int nE = E_ + n;
  int nb = (n + 255) / 256;

  uintptr_t base = (uintptr_t)d_ws;
  size_t off = 0;
  auto alloc = [&](size_t bytes) -> void* {
    void* p = (void*)(base + off);
    off += (bytes + 255) & ~(size_t)255;
    return p;
  };
  float* t_emb = (float*)alloc(32 * 4);
  short* pk    = (short*)alloc(114688 * 2);
  short* pk_l1_t = pk;
  short* pk_l1_m = pk + 16384;
  short* pk_l1_2 = pk + 32768;
  short* pk_l2_t = pk + 49152;
  short* pk_l2_m = pk + 65536;
  short* pk_l2_2 = pk + 81920;
  short* pk_bp_t = pk + 98304;
  short* pk_bp_b = pk + 106496;
  float* X0   = (float*)alloc((size_t)n * 128 * 4);
  float* X1   = (float*)alloc((size_t)n * 128 * 4);
  ushort_t* Sb  = (ushort_t*)alloc((size_t)n * 128 * 2);
  ushort_t* Pbf = (ushort_t*)alloc((size_t)n * 128 * 2);
  ushort_t* Qbf = (ushort_t*)alloc((size_t)n * 128 * 2);
  int*   deg    = (int*)alloc((size_t)n * 4);
  int*   tmp    = (int*)alloc((size_t)n * 4);
  int*   bsum   = (int*)alloc(256 * 4);
  int*   rowp   = (int*)alloc(((size_t)n + 1) * 4);
  int*   cursor = (int*)alloc((size_t)n * 4);
  int*   csrsrc = (int*)alloc((size_t)nE * 4);
  int*   csrdst = (int*)alloc((size_t)nE * 4);
  float4* aux4  = (float4*)alloc((size_t)nE * 16);
  float* auxd   = (float*)alloc((size_t)nE * 4);
  float* degf   = (float*)alloc((size_t)n * 4);
  float* pos1   = (float*)alloc((size_t)n * 3 * 4);
  ushort_t* Ubf = Pbf;           // reuse after layer-2 aggregate
  ushort_t* Vbf = Qbf;

  // constants / packs / input assembly
  k_time_embed<<<1, 64, 0, stream>>>(tt, te_w1, te_b1, te_w2, te_b2, t_emb);
  k_pack_all<<<448, 256, 0, stream>>>(l1_nm_w1, l1_nm_w1 + 16384, l1_nm_w2,
                                      l2_nm_w1, l2_nm_w1 + 16384, l2_nm_w2,
                                      bp_w1, bp_w1 + 128 * 64, pk);
  k_build_xin<<<(n * 32 + 255) / 256, 256, 0, stream>>>(x_t, cond, t_emb, X0, n);

  // CSR by dst (shared by both layers)
  k_deg_init<<<nb, 256, 0, stream>>>(deg, n);
  k_deg_count<<<(E_ + 255) / 256, 256, 0, stream>>>(ei + E_, E_, deg);
  k_scan1<<<nb, 256, 0, stream>>>(deg, tmp, bsum, n);
  k_scan2<<<1, 256, 0, stream>>>(bsum, nb);
  k_scan3<<<nb, 256, 0, stream>>>(deg, tmp, bsum, rowp, cursor, n);
  k_scatter<<<(nE + 255) / 256, 256, 0, stream>>>(ei, E_, nE, cursor, csrsrc, csrdst);

  int nagg = (n + 3) / 4;
  int naux = (nE + 255) / 256;

  // ---- layer 1
  k_aux1<<<naux, 256, 0, stream>>>(csrsrc, csrdst, nE, pos,
                                   l1_cm_w1, l1_cm_b1, l1_cm_w2, l1_cm_b2, aux4);
  k_mgemm<128,false,true><<<512, 256, 0, stream>>>(X0, pk_l1_t, l1_nm_b1, nullptr, nullptr, Pbf, nullptr, n);
  k_mgemm<128,false,true><<<512, 256, 0, stream>>>(X0, pk_l1_m, nullptr,  nullptr, nullptr, Qbf, nullptr, n);
  k_aggregate<true><<<nagg, 256, 0, stream>>>(rowp, csrsrc, aux4, nullptr, Pbf, Qbf,
      l1_nm_w1 + 256 * 128, pos, pos1, degf, Sb, n);
  k_mgemm<128,true,false><<<512, 256, 0, stream>>>(Sb, pk_l1_2, l1_nm_b2, X0, degf, X1, nullptr, n);

  // ---- layer 2 (pos2 dead -> no coord path)
  k_aux2<<<naux, 256, 0, stream>>>(csrsrc, csrdst, nE, pos1, auxd);
  k_mgemm<128,false,true><<<512, 256, 0, stream>>>(X1, pk_l2_t, l2_nm_b1, nullptr, nullptr, Pbf, nullptr, n);
  k_mgemm<128,false,true><<<512, 256, 0, stream>>>(X1, pk_l2_m, nullptr,  nullptr, nullptr, Qbf, nullptr, n);
  k_aggregate<false><<<nagg, 256, 0, stream>>>(rowp, csrsrc, nullptr, auxd, Pbf, Qbf,
      l2_nm_w1 + 256 * 128, nullptr, nullptr, nullptr, Sb, n);
  // final post-GEMM also writes d_out[:, :64]
  k_mgemm<128,true,false><<<512, 256, 0, stream>>>(Sb, pk_l2_2, l2_nm_b2, X1, degf, X0, (float*)d_out, n);

  // ---- bond predictor (U,V bf16, reuse P/Q buffers)
  k_mgemm<64,false,true><<<512, 256, 0, stream>>>(X0, pk_bp_t, bp_b1,  nullptr, nullptr, Ubf, nullptr, n);
  k_mgemm<64,false,true><<<512, 256, 0, stream>>>(X0, pk_bp_b, nullptr, nullptr, nullptr, Vbf, nullptr, n);
  k_bond<<<(E_ * 16 + 255) / 256, 256, 0, stream>>>(ei, E_, Ubf, Vbf, bp_w2, bp_b2,
                                                    (float*)d_out + (size_t)n * 64);
}